// Round 14
// baseline (220.116 us; speedup 1.0000x reference)
//
#include <hip/hip_runtime.h>
#include <cmath>

constexpr int NB   = 32768;   // batch rows
constexpr int IND  = 512;
constexpr int HIDD = 64;
constexpr int CM   = 128;     // COMM
constexpr int NP   = 2048;    // num protos
constexpr float BETA  = 0.25f;
constexpr float ENT_W = 0.1f;
constexpr float EPSV  = 1e-8f;

typedef __attribute__((ext_vector_type(8))) short short8v;   // 8 x bf16
typedef __attribute__((ext_vector_type(4))) float f32x4v;

__device__ __forceinline__ float4 ld4(const float* p){ return *reinterpret_cast<const float4*>(p); }
__device__ __forceinline__ void  st4(float* p, float4 v){ *reinterpret_cast<float4*>(p) = v; }

__device__ __forceinline__ unsigned short f2bf(float f){
  union { float f; unsigned u; } v; v.f = f;
  unsigned r = v.u + 0x7fffu + ((v.u >> 16) & 1u);   // RNE
  return (unsigned short)(r >> 16);
}
__device__ __forceinline__ float bf2f(unsigned short u){
  union { unsigned u; float f; } v; v.u = ((unsigned)u) << 16;
  return v.f;
}
__device__ __forceinline__ short8v cvt8(float4 a, float4 b){
  short8v r;
  r[0]=(short)f2bf(a.x); r[1]=(short)f2bf(a.y); r[2]=(short)f2bf(a.z); r[3]=(short)f2bf(a.w);
  r[4]=(short)f2bf(b.x); r[5]=(short)f2bf(b.y); r[6]=(short)f2bf(b.z); r[7]=(short)f2bf(b.w);
  return r;
}

__device__ __forceinline__ float wave_sum(float v){
  #pragma unroll
  for (int m = 1; m < 64; m <<= 1) v += __shfl_xor(v, m, 64);
  return v;
}

// async global->LDS (dest = wave-uniform base + lane*size)
typedef __attribute__((address_space(1))) unsigned int gu32;
typedef __attribute__((address_space(3))) unsigned int su32;
__device__ __forceinline__ void gload_lds16(const void* g, void* s){
  __builtin_amdgcn_global_load_lds((const gu32*)g, (su32*)s, 16, 0, 0);
}
__device__ __forceinline__ void gload_lds4(const void* g, void* s){
  __builtin_amdgcn_global_load_lds((const gu32*)g, (su32*)s, 4, 0, 0);
}
__device__ __forceinline__ void barrier_raw(){
  __builtin_amdgcn_sched_barrier(0);
  __builtin_amdgcn_s_barrier();
  __builtin_amdgcn_sched_barrier(0);
}

// ---------------- prep: proto norms + bf16 protos + transposed bf16 weights ----------------
__global__ __launch_bounds__(256) void k_prep(const float* __restrict__ protos,
                                              float* __restrict__ normp2,
                                              unsigned short* __restrict__ pBF,
                                              const float* __restrict__ W_emb,
                                              const float* __restrict__ W1,
                                              const float* __restrict__ W2,
                                              const float* __restrict__ Wmu,
                                              const float* __restrict__ Wvar,
                                              unsigned short* __restrict__ WembT,
                                              unsigned short* __restrict__ W1T,
                                              unsigned short* __restrict__ W2T,
                                              unsigned short* __restrict__ WmuT,
                                              unsigned short* __restrict__ WvarT){
  const int b = blockIdx.x, tid = threadIdx.x;
  if (b < 8){
    const int p = b * 256 + tid;
    const float* row = protos + (size_t)p * CM;
    float s = 0.f;
    #pragma unroll
    for (int k = 0; k < CM; k += 4){
      float4 v = ld4(row + k);
      s += v.x*v.x + v.y*v.y + v.z*v.z + v.w*v.w;
      ushort4 u; u.x = f2bf(v.x); u.y = f2bf(v.y); u.z = f2bf(v.z); u.w = f2bf(v.w);
      *reinterpret_cast<ushort4*>(&pBF[(size_t)p * CM + k]) = u;
    }
    normp2[p] = s;
  } else if (b < 16){
    const int nb = (b - 8) * 8;                  // 8 n-rows of WembT per block
    for (int i = tid; i < 8*512; i += 256){
      const int n = nb + (i >> 9), k = i & 511;
      WembT[n*512 + k] = f2bf(W_emb[k*64 + n]);
    }
  } else if (b == 16){
    for (int i = tid; i < 64*64; i += 256){
      const int n = i >> 6, k = i & 63;
      W1T[n*64 + k] = f2bf(W1[k*64 + n]);
    }
  } else if (b == 17){
    for (int i = tid; i < 128*64; i += 256){
      const int n = i >> 6, k = i & 63;
      W2T[n*64 + k] = f2bf(W2[k*128 + n]);
    }
  } else if (b < 20){
    const int nb = (b - 18) * 64;
    for (int i = tid; i < 64*128; i += 256){
      const int n = nb + (i >> 7), k = i & 127;
      WmuT[n*128 + k] = f2bf(Wmu[k*128 + n]);
    }
  } else {
    const int nb = (b - 20) * 64;
    for (int i = tid; i < 64*128; i += 256){
      const int n = nb + (i >> 7), k = i & 127;
      WvarT[n*128 + k] = f2bf(Wvar[k*128 + n]);
    }
  }
}

// ---------------- mega: MLP + dual GEMM + sample/kld + both proto phases, one kernel ----------------
// R14 = R10 structure + T15-lite: each proto slot's epilogue (argmin/exp) is deferred
// one slot and runs (register-only) while the NEXT slot's ds_reads+MFMAs issue.
__global__ __launch_bounds__(512, 4) void mega(const float* __restrict__ x,
    const unsigned short* __restrict__ WembT, const float* __restrict__ b_emb,
    const unsigned short* __restrict__ W1T,   const float* __restrict__ b1,
    const unsigned short* __restrict__ W2T,   const float* __restrict__ b2,
    const unsigned short* __restrict__ WmuT,  const float* __restrict__ bmu,
    const unsigned short* __restrict__ WvarT, const float* __restrict__ bvar,
    const float* __restrict__ epsIn,
    const unsigned short* __restrict__ pBF, const float* __restrict__ normp2,
    const float* __restrict__ protosF,
    float* __restrict__ outA, float* __restrict__ approx_part,
    float* __restrict__ commit_part, float* __restrict__ kld_part)
{
  __shared__ __align__(16) unsigned short SH[36864];
  __shared__ float Pn[3][64];
  __shared__ float nm2_s[2][64];
  __shared__ float bw[2][64];
  __shared__ int   iw[2][64];
  __shared__ float sw[2][64];
  __shared__ float srow_s[64];
  __shared__ int   bidx_s[64];
  __shared__ float redbuf[8];

  unsigned short* muS = SH;
  float* approxl      = (float*)(SH + 8192);
  unsigned short* PsU = SH + 12288;
  unsigned short* Xs  = PsU;
  unsigned short* h1s = PsU + 4096;
  unsigned short* h2s = PsU + 8192;
  unsigned short* h3s = PsU + 12288;
  unsigned short* sS  = PsU + 16384;

  const int tid = threadIdx.x;
  const int w = tid >> 6, l = tid & 63;
  const int lr = l >> 4, lc = l & 15;
  const int rowbase = blockIdx.x * 64;

  // ================= fwd portion =================
  const int rq = w & 3, nh = w >> 2;
  const int row = rq*16 + lc;

  // ---- layer 1: h1 = x @ W_emb + b_emb (K=512) ----
  f32x4v acc1[2];
  acc1[0] = (f32x4v){0.f,0.f,0.f,0.f}; acc1[1] = (f32x4v){0.f,0.f,0.f,0.f};
  const int srow = tid >> 3, sq = tid & 7;   // 8 threads/row x 8 floats
  const float* xrow = x + (size_t)(rowbase + srow) * IND + sq*8;
  for (int kc8 = 0; kc8 < 8; kc8++){
    float4 v0 = ld4(xrow + kc8*64);
    float4 v1 = ld4(xrow + kc8*64 + 4);
    __syncthreads();   // previous chunk's Xs reads complete
    *reinterpret_cast<short8v*>(&Xs[(srow*64 + sq*8) ^ ((srow & 7) << 3)]) = cvt8(v0, v1);
    __syncthreads();
    #pragma unroll
    for (int ks = 0; ks < 2; ks++){
      const int ai = (row*64 + ks*32 + lr*8) ^ ((row & 7) << 3);
      short8v af = *reinterpret_cast<const short8v*>(&Xs[ai]);
      #pragma unroll
      for (int nt = 0; nt < 2; nt++){
        const int n = nh*32 + nt*16 + lc;
        short8v bf = *reinterpret_cast<const short8v*>(&WembT[(size_t)n*512 + kc8*64 + ks*32 + lr*8]);
        acc1[nt] = __builtin_amdgcn_mfma_f32_16x16x32_bf16(af, bf, acc1[nt], 0, 0, 0);
      }
    }
  }
  __syncthreads();   // last Xs reads done
  #pragma unroll
  for (int nt = 0; nt < 2; nt++){
    const int col = nh*32 + nt*16 + lc;
    const float bb = b_emb[col];
    #pragma unroll
    for (int r = 0; r < 4; r++){
      const int row2 = rq*16 + lr*4 + r;
      h1s[(row2*64 + col) ^ ((row2 & 7) << 3)] = f2bf(acc1[nt][r] + bb);
    }
  }
  __syncthreads();

  // ---- layer 2: h2 = relu(h1 @ W1 + b1) (K=64) ----
  f32x4v acc2[2];
  acc2[0] = (f32x4v){0.f,0.f,0.f,0.f}; acc2[1] = (f32x4v){0.f,0.f,0.f,0.f};
  #pragma unroll
  for (int ks = 0; ks < 2; ks++){
    const int ai = (row*64 + ks*32 + lr*8) ^ ((row & 7) << 3);
    short8v af = *reinterpret_cast<const short8v*>(&h1s[ai]);
    #pragma unroll
    for (int nt = 0; nt < 2; nt++){
      const int n = nh*32 + nt*16 + lc;
      short8v bf = *reinterpret_cast<const short8v*>(&W1T[(size_t)n*64 + ks*32 + lr*8]);
      acc2[nt] = __builtin_amdgcn_mfma_f32_16x16x32_bf16(af, bf, acc2[nt], 0, 0, 0);
    }
  }
  __syncthreads();
  #pragma unroll
  for (int nt = 0; nt < 2; nt++){
    const int col = nh*32 + nt*16 + lc;
    const float bb = b1[col];
    #pragma unroll
    for (int r = 0; r < 4; r++){
      const int row2 = rq*16 + lr*4 + r;
      h2s[(row2*64 + col) ^ ((row2 & 7) << 3)] = f2bf(fmaxf(acc2[nt][r] + bb, 0.f));
    }
  }
  __syncthreads();

  // ---- layer 3: h3 = relu(h2 @ W2 + b2) (K=64, N=128) ----
  f32x4v acc3[4];
  #pragma unroll
  for (int nt = 0; nt < 4; nt++) acc3[nt] = (f32x4v){0.f,0.f,0.f,0.f};
  #pragma unroll
  for (int ks = 0; ks < 2; ks++){
    const int ai = (row*64 + ks*32 + lr*8) ^ ((row & 7) << 3);
    short8v af = *reinterpret_cast<const short8v*>(&h2s[ai]);
    #pragma unroll
    for (int nt = 0; nt < 4; nt++){
      const int n = nh*64 + nt*16 + lc;
      short8v bf = *reinterpret_cast<const short8v*>(&W2T[(size_t)n*64 + ks*32 + lr*8]);
      acc3[nt] = __builtin_amdgcn_mfma_f32_16x16x32_bf16(af, bf, acc3[nt], 0, 0, 0);
    }
  }
  __syncthreads();
  #pragma unroll
  for (int nt = 0; nt < 4; nt++){
    const int col = nh*64 + nt*16 + lc;
    const float bb = b2[col];
    #pragma unroll
    for (int r = 0; r < 4; r++){
      const int row2 = rq*16 + lr*4 + r;
      h3s[(row2*128 + col) ^ ((row2 & 7) << 3)] = f2bf(fmaxf(acc3[nt][r] + bb, 0.f));
    }
  }
  __syncthreads();

  // ---- dual GEMM: mu / logvar (K=128, N=128) ----
  f32x4v accM[4], accV[4];
  #pragma unroll
  for (int nt = 0; nt < 4; nt++){ accM[nt] = (f32x4v){0.f,0.f,0.f,0.f}; accV[nt] = (f32x4v){0.f,0.f,0.f,0.f}; }
  #pragma unroll
  for (int ks = 0; ks < 4; ks++){
    const int ai = (row*128 + ks*32 + lr*8) ^ ((row & 7) << 3);
    short8v af = *reinterpret_cast<const short8v*>(&h3s[ai]);
    #pragma unroll
    for (int nt = 0; nt < 4; nt++){
      const int n = nh*64 + nt*16 + lc;
      short8v bM = *reinterpret_cast<const short8v*>(&WmuT [(size_t)n*128 + ks*32 + lr*8]);
      short8v bV = *reinterpret_cast<const short8v*>(&WvarT[(size_t)n*128 + ks*32 + lr*8]);
      accM[nt] = __builtin_amdgcn_mfma_f32_16x16x32_bf16(af, bM, accM[nt], 0, 0, 0);
      accV[nt] = __builtin_amdgcn_mfma_f32_16x16x32_bf16(af, bV, accV[nt], 0, 0, 0);
    }
  }
  __syncthreads();   // h3s reads done -> sS overlay (and Ps[0]) now writable

  // stage proto chunk 0 into Ps buf0 early: latency hides under sampling epilogue
  #define STAGE(pc, buf) {                                                        \
    _Pragma("unroll")                                                             \
    for (int j = 0; j < 2; j++){                                                  \
      const int p = w*8 + j*4 + (l >> 4);                                         \
      const int g = l & 15;                                                       \
      gload_lds16(&pBF[(size_t)((pc) + p)*CM + ((g*8) ^ ((p & 7)*8))],            \
                  &PsU[(size_t)(buf)*8192 + (w*8 + j*4)*CM]);                     \
    }                                                                             \
    if (w == 0) gload_lds4(&normp2[(pc) + l], &Pn[buf][0]);                       \
  }
  #define VWAIT_PEND() { if (w == 0) asm volatile("s_waitcnt vmcnt(3)" ::: "memory"); \
                         else        asm volatile("s_waitcnt vmcnt(2)" ::: "memory"); }
  #define VWAIT_ALL()  asm volatile("s_waitcnt vmcnt(0)" ::: "memory")

  STAGE(0, 0);

  // ---- sampling epilogue: mu/sample -> LDS bf16, kld partial, block-local ||mu||^2 ----
  {
    float kl = 0.f;
    float m2[4] = {0.f, 0.f, 0.f, 0.f};
    #pragma unroll
    for (int nt = 0; nt < 4; nt++){
      const int col = nh*64 + nt*16 + lc;
      const float bm = bmu[col], bv = bvar[col];
      #pragma unroll
      for (int r = 0; r < 4; r++){
        const int row2 = rq*16 + lr*4 + r;
        const float mu = accM[nt][r] + bm;
        const float lv = accV[nt][r] + bv;
        const float s2 = __expf(0.5f * lv);
        const float sa = mu + s2 * epsIn[(size_t)(rowbase + row2)*CM + col];
        kl += 1.f + lv - mu*mu - s2*s2;
        m2[r] += mu*mu;
        const int li = (row2*128 + col) ^ ((row2 & 7) << 3);
        muS[li] = f2bf(mu);
        sS [li] = f2bf(sa);
      }
    }
    #pragma unroll
    for (int m = 1; m < 16; m <<= 1){
      #pragma unroll
      for (int r = 0; r < 4; r++) m2[r] += __shfl_xor(m2[r], m, 64);
    }
    if (lc == 0){
      #pragma unroll
      for (int r = 0; r < 4; r++) nm2_s[nh][rq*16 + lr*4 + r] = m2[r];
    }
    const float kw = wave_sum(kl);
    if (l == 0) redbuf[w] = kw;
  }
  __syncthreads();   // muS/sS/nm2_s/redbuf visible
  if (tid == 0) kld_part[blockIdx.x] = redbuf[0]+redbuf[1]+redbuf[2]+redbuf[3]
                                     + redbuf[4]+redbuf[5]+redbuf[6]+redbuf[7];

  // ================= proto portion =================
  const int rw = w & 1;            // rows half (32 rows)
  const int pw = (w >> 1) & 1;     // protos half of chunk (32)
  const int mat = w >> 2;          // 0: sample/argmin, 1: mu/exp

  const unsigned short* Abase = mat ? muS : sS;
  short8v af[2][4];
  #pragma unroll
  for (int mt = 0; mt < 2; mt++){
    const int ar = rw*32 + mt*16 + lc;
    #pragma unroll
    for (int ks = 0; ks < 4; ks++)
      af[mt][ks] = *reinterpret_cast<const short8v*>(&Abase[(ar*128 + ks*32 + lr*8) ^ ((ar & 7) << 3)]);
  }
  float nmn[8];   // -0.125 * ||mu||^2 per row
  #pragma unroll
  for (int mt = 0; mt < 2; mt++)
    #pragma unroll
    for (int r = 0; r < 4; r++){
      const int rr = rw*32 + mt*16 + lr*4 + r;
      nmn[mt*4+r] = -0.125f * (nm2_s[0][rr] + nm2_s[1][rr]);
    }
  __syncthreads();   // all sS reads done -> approxl overlay writable
  for (int t = tid; t < NP; t += 512) approxl[t] = 0.f;

  float best[8]; int bidx[8]; float sr[8];
  #pragma unroll
  for (int i = 0; i < 8; i++){ best[i] = 3.4e38f; bidx[i] = 0; sr[i] = 0.f; }

  // ---------------- phase A (epilogue deferred one slot) ----------------
  f32x4v accP[2][2];
  #pragma unroll
  for (int mt = 0; mt < 2; mt++)
    #pragma unroll
    for (int nt = 0; nt < 2; nt++) accP[mt][nt] = (f32x4v){0.f,0.f,0.f,0.f};
  float npvP0 = 0.f, npvP1 = 0.f;
  int pgbP = 0;

  #define EPI_A() {                                                               \
    if (mat == 0){                                                                \
      _Pragma("unroll")                                                           \
      for (int nt = 0; nt < 2; nt++){                                             \
        const int pg = pgbP + pw*32 + nt*16 + lc;                                 \
        const float npv = nt ? npvP1 : npvP0;                                     \
        _Pragma("unroll")                                                         \
        for (int mt = 0; mt < 2; mt++)                                            \
          _Pragma("unroll")                                                       \
          for (int r = 0; r < 4; r++){                                            \
            const float sc = fmaf(-2.f, accP[mt][nt][r], npv);                    \
            if (sc < best[mt*4+r]){ best[mt*4+r] = sc; bidx[mt*4+r] = pg; }       \
          }                                                                       \
      }                                                                           \
    } else {                                                                      \
      _Pragma("unroll")                                                           \
      for (int nt = 0; nt < 2; nt++){                                             \
        const float pvn = -0.125f * (nt ? npvP1 : npvP0);                         \
        _Pragma("unroll")                                                         \
        for (int mt = 0; mt < 2; mt++)                                            \
          _Pragma("unroll")                                                       \
          for (int r = 0; r < 4; r++)                                             \
            sr[mt*4+r] += __expf(fmaf(0.25f, accP[mt][nt][r], nmn[mt*4+r] + pvn));\
      }                                                                           \
    }                                                                             \
  }

  int cur = 0;
  for (int c = 0; c < 32; c++){
    const int nxt = (cur == 2) ? 0 : cur + 1;
    if (c < 31){ STAGE((c+1)*64, nxt); VWAIT_PEND(); }
    else       { VWAIT_ALL(); }
    barrier_raw();
    const float npv0 = Pn[cur][pw*32 + lc];
    const float npv1 = Pn[cur][pw*32 + 16 + lc];
    const unsigned short* pb = &PsU[(size_t)cur*8192];
    f32x4v acc[2][2];
    #pragma unroll
    for (int mt = 0; mt < 2; mt++)
      #pragma unroll
      for (int nt = 0; nt < 2; nt++) acc[mt][nt] = (f32x4v){0.f,0.f,0.f,0.f};
    #pragma unroll
    for (int ks = 0; ks < 4; ks++){
      const int pl0 = pw*32 + lc;
      const int pl1 = pw*32 + 16 + lc;
      short8v pf0 = *reinterpret_cast<const short8v*>(&pb[(pl0*CM + ks*32 + lr*8) ^ ((pl0 & 7) << 3)]);
      short8v pf1 = *reinterpret_cast<const short8v*>(&pb[(pl1*CM + ks*32 + lr*8) ^ ((pl1 & 7) << 3)]);
      #pragma unroll
      for (int mt = 0; mt < 2; mt++){
        acc[mt][0] = __builtin_amdgcn_mfma_f32_16x16x32_bf16(af[mt][ks], pf0, acc[mt][0], 0, 0, 0);
        acc[mt][1] = __builtin_amdgcn_mfma_f32_16x16x32_bf16(af[mt][ks], pf1, acc[mt][1], 0, 0, 0);
      }
    }
    if (c > 0) EPI_A();          // prev slot's epilogue overlaps this slot's MFMAs
    #pragma unroll
    for (int mt = 0; mt < 2; mt++)
      #pragma unroll
      for (int nt = 0; nt < 2; nt++) accP[mt][nt] = acc[mt][nt];
    npvP0 = npv0; npvP1 = npv1; pgbP = c*64;
    cur = nxt;
  }
  EPI_A();                       // slot 31's epilogue
  #undef EPI_A

  if (mat == 0){
    #pragma unroll
    for (int m = 1; m < 16; m <<= 1){
      #pragma unroll
      for (int i = 0; i < 8; i++){
        const float ob = __shfl_xor(best[i], m, 64);
        const int   oi = __shfl_xor(bidx[i], m, 64);
        if (ob < best[i] || (ob == best[i] && oi < bidx[i])){ best[i] = ob; bidx[i] = oi; }
      }
    }
    if (lc == 0){
      #pragma unroll
      for (int mt = 0; mt < 2; mt++)
        #pragma unroll
        for (int r = 0; r < 4; r++){
          const int rr = rw*32 + mt*16 + lr*4 + r;
          bw[pw][rr] = best[mt*4+r];
          iw[pw][rr] = bidx[mt*4+r];
        }
    }
  } else {
    #pragma unroll
    for (int m = 1; m < 16; m <<= 1){
      #pragma unroll
      for (int i = 0; i < 8; i++) sr[i] += __shfl_xor(sr[i], m, 64);
    }
    if (lc == 0){
      #pragma unroll
      for (int mt = 0; mt < 2; mt++)
        #pragma unroll
        for (int r = 0; r < 4; r++){
          const int rr = rw*32 + mt*16 + lr*4 + r;
          sw[pw][rr] = sr[mt*4+r];
        }
    }
  }
  __syncthreads();
  if (tid < 64){
    float b0 = bw[0][tid]; int i0 = iw[0][tid];
    const float b1 = bw[1][tid]; const int i1 = iw[1][tid];
    if (b1 < b0 || (b1 == b0 && i1 < i0)){ b0 = b1; i0 = i1; }
    bidx_s[tid] = i0;
    srow_s[tid] = sw[0][tid] + sw[1][tid] + (float)NP * EPSV;
  }
  STAGE(0, 0);   // prefetch phase-B chunk 0 (buf0 last read at chunk 30; sync above)
  __syncthreads();

  // out rows = protos[idx] (fp32) + commitment partial (mu from LDS)
  {
    const int orow = tid >> 3, cp = tid & 7;
    const int rowg = rowbase + orow;
    const int idx = bidx_s[orow];
    float cl = 0.f;
    #pragma unroll
    for (int c4 = 0; c4 < 4; c4++){
      const int cc = c4*32 + cp*4;
      float4 q = ld4(protosF + (size_t)idx * CM + cc);
      const int li = (orow*128 + cc) ^ ((orow & 7) << 3);
      ushort4 mb = *reinterpret_cast<const ushort4*>(&muS[li]);
      st4(outA + (size_t)rowg * CM + cc, q);
      const float dx=q.x-bf2f(mb.x), dy=q.y-bf2f(mb.y), dz=q.z-bf2f(mb.z), dw=q.w-bf2f(mb.w);
      cl += dx*dx + dy*dy + dz*dz + dw*dw;
    }
    const float cw = wave_sum(cl);
    if (l == 0) redbuf[w] = cw;
  }
  float rs[8]; float epsc = 0.f;
  #pragma unroll
  for (int mt = 0; mt < 2; mt++)
    #pragma unroll
    for (int r = 0; r < 4; r++){
      rs[mt*4+r] = 1.0f / srow_s[rw*32 + mt*16 + lr*4 + r];
      epsc += rs[mt*4+r];
    }
  epsc *= EPSV;
  if (mat == 0){
    #pragma unroll
    for (int mt = 0; mt < 2; mt++){
      const int ar = rw*32 + mt*16 + lc;
      #pragma unroll
      for (int ks = 0; ks < 4; ks++)
        af[mt][ks] = *reinterpret_cast<const short8v*>(&muS[(ar*128 + ks*32 + lr*8) ^ ((ar & 7) << 3)]);
    }
  }
  __syncthreads();
  if (tid == 0) commit_part[blockIdx.x] = redbuf[0]+redbuf[1]+redbuf[2]+redbuf[3]
                                        + redbuf[4]+redbuf[5]+redbuf[6]+redbuf[7];

  // ---------------- phase B (epilogue deferred one slot) ----------------
  const int pq = w >> 1;   // 16-proto quarter
  f32x4v accBP[2];
  accBP[0] = (f32x4v){0.f,0.f,0.f,0.f}; accBP[1] = (f32x4v){0.f,0.f,0.f,0.f};
  float npvPB = 0.f; int cPB = 0;

  #define EPI_B() {                                                               \
    const float pvn = -0.125f * npvPB;                                            \
    float cs = epsc;                                                              \
    _Pragma("unroll")                                                             \
    for (int mt = 0; mt < 2; mt++)                                                \
      _Pragma("unroll")                                                           \
      for (int r = 0; r < 4; r++){                                                \
        const float e = __expf(fmaf(0.25f, accBP[mt][r], nmn[mt*4+r] + pvn));     \
        cs = fmaf(e, rs[mt*4+r], cs);                                             \
      }                                                                           \
    cs += __shfl_xor(cs, 16, 64);                                                 \
    cs += __shfl_xor(cs, 32, 64);                                                 \
    if (l < 16) atomicAdd(&approxl[cPB*64 + pq*16 + lc], cs);                     \
  }

  cur = 0;
  for (int c = 0; c < 32; c++){
    const int nxt = (cur == 2) ? 0 : cur + 1;
    if (c < 31){ STAGE((c+1)*64, nxt); VWAIT_PEND(); }
    else       { VWAIT_ALL(); }
    barrier_raw();
    const int pl = pq*16 + lc;
    const float npv = Pn[cur][pl];
    const unsigned short* pb = &PsU[(size_t)cur*8192];
    f32x4v accB[2];
    accB[0] = (f32x4v){0.f,0.f,0.f,0.f};
    accB[1] = (f32x4v){0.f,0.f,0.f,0.f};
    #pragma unroll
    for (int ks = 0; ks < 4; ks++){
      short8v pf = *reinterpret_cast<const short8v*>(&pb[(pl*CM + ks*32 + lr*8) ^ ((pl & 7) << 3)]);
      accB[0] = __builtin_amdgcn_mfma_f32_16x16x32_bf16(af[0][ks], pf, accB[0], 0, 0, 0);
      accB[1] = __builtin_amdgcn_mfma_f32_16x16x32_bf16(af[1][ks], pf, accB[1], 0, 0, 0);
    }
    if (c > 0) EPI_B();          // prev slot's exp/normalize overlaps this slot's MFMAs
    accBP[0] = accB[0]; accBP[1] = accB[1];
    npvPB = npv; cPB = c;
    cur = nxt;
  }
  EPI_B();                       // slot 31's epilogue
  #undef EPI_B

  __syncthreads();
  for (int t = tid; t < NP; t += 512)
    approx_part[(size_t)blockIdx.x * NP + t] = approxl[t];
  #undef STAGE
  #undef VWAIT_PEND
  #undef VWAIT_ALL
}

// ---------------- final reductions ----------------
__global__ __launch_bounds__(256) void k4a(const float* __restrict__ approx_part,
                                           float* __restrict__ ent_part){
  __shared__ float red[128];
  const int tid = threadIdx.x;
  const int p = blockIdx.x * 32 + (tid & 31);
  const int slice = tid >> 5;            // 0..7
  float s = 0.f;
  for (int b = slice; b < 512; b += 8) s += approx_part[(size_t)b * NP + p];
  s += __shfl_xor(s, 32, 64);
  if ((tid & 63) < 32) red[(tid >> 6)*32 + (tid & 31)] = s;
  __syncthreads();
  if (tid < 32){
    const float a = (red[tid] + red[32+tid] + red[64+tid] + red[96+tid]) * (1.0f / 32768.0f);
    float t = -a * logf(a);
    #pragma unroll
    for (int m = 1; m < 32; m <<= 1) t += __shfl_xor(t, m, 32);
    if (tid == 0) ent_part[blockIdx.x] = t;
  }
}

__global__ __launch_bounds__(256) void k4b(const float* __restrict__ kld_part,
                                           const float* __restrict__ commit_part,
                                           const float* __restrict__ ent_part,
                                           float* __restrict__ outs){
  __shared__ float redbuf[8];
  const int tid = threadIdx.x;
  float k = 0.f, c = 0.f;
  for (int i = tid; i < 512; i += 256){ k += kld_part[i]; c += commit_part[i]; }
  float kw = wave_sum(k), cw = wave_sum(c);
  if ((tid & 63) == 0){ redbuf[tid >> 6] = kw; redbuf[4 + (tid >> 6)] = cw; }
  __syncthreads();
  if (tid == 0){
    float ks = redbuf[0] + redbuf[1] + redbuf[2] + redbuf[3];
    float cs = redbuf[4] + redbuf[5] + redbuf[6] + redbuf[7];
    float es = 0.f;
    for (int i = 0; i < 64; i++) es += ent_part[i];
    float kld = -0.5f * ks / 32768.0f;
    float m = cs / (32768.0f * 128.0f);
    float vq = BETA * m + m + ENT_W * es;
    outs[0] = kld + vq;   // KL_W = 1
    outs[1] = kld;
  }
}

extern "C" void kernel_launch(void* const* d_in, const int* in_sizes, int n_in,
                              void* d_out, int out_size, void* d_ws, size_t ws_size,
                              hipStream_t stream){
  const float* x      = (const float*)d_in[0];
  const float* epsIn  = (const float*)d_in[1];
  const float* W_emb  = (const float*)d_in[2];
  const float* b_emb  = (const float*)d_in[3];
  const float* W1     = (const float*)d_in[4];
  const float* b1     = (const float*)d_in[5];
  const float* W2     = (const float*)d_in[6];
  const float* b2     = (const float*)d_in[7];
  const float* W_mu   = (const float*)d_in[8];
  const float* b_mu   = (const float*)d_in[9];
  const float* W_var  = (const float*)d_in[10];
  const float* b_var  = (const float*)d_in[11];
  const float* protos = (const float*)d_in[12];
  float* out = (float*)d_out;
  float* ws = (float*)d_ws;

  const size_t M1 = 1024u * 1024u;
  float* approx_part = ws;                    // [0,1M) floats (512*2048)
  float* tail = ws + M1;
  float* normp2      = tail;                  // 2048
  float* kld_part    = normp2 + 2048;         // 512
  float* commit_part = kld_part + 512;        // 512
  float* ent_part    = commit_part + 512;     // 64
  unsigned short* pBF   = (unsigned short*)(ent_part + 64);  // 2048*128
  unsigned short* WembT = pBF + (size_t)NP*CM;               // 64*512
  unsigned short* W1T   = WembT + 64*512;                    // 64*64
  unsigned short* W2T   = W1T + 64*64;                       // 128*64
  unsigned short* WmuT  = W2T + 128*64;                      // 128*128
  unsigned short* WvarT = WmuT + 128*128;                    // 128*128

  k_prep<<<22, 256, 0, stream>>>(protos, normp2, pBF, W_emb, W1, W2, W_mu, W_var,
                                 WembT, W1T, W2T, WmuT, WvarT);
  mega<<<NB/64, 512, 0, stream>>>(x, WembT, b_emb, W1T, b1, W2T, b2,
                                  WmuT, b_mu, WvarT, b_var, epsIn,
                                  pBF, normp2, protos,
                                  out, approx_part, commit_part, kld_part);
  k4a<<<64, 256, 0, stream>>>(approx_part, ent_part);
  k4b<<<1, 256, 0, stream>>>(kld_part, commit_part, ent_part, out + (size_t)NB * CM);
}

// Round 15
// 154.960 us; speedup vs baseline: 1.4205x; 1.4205x over previous
//
#include <hip/hip_runtime.h>
#include <cmath>

constexpr int NB   = 32768;   // batch rows
constexpr int IND  = 512;
constexpr int HIDD = 64;
constexpr int CM   = 128;     // COMM
constexpr int NP   = 2048;    // num protos
constexpr float BETA  = 0.25f;
constexpr float ENT_W = 0.1f;
constexpr float EPSV  = 1e-8f;

typedef __attribute__((ext_vector_type(8))) short short8v;   // 8 x bf16
typedef __attribute__((ext_vector_type(4))) float f32x4v;

__device__ __forceinline__ float4 ld4(const float* p){ return *reinterpret_cast<const float4*>(p); }
__device__ __forceinline__ void  st4(float* p, float4 v){ *reinterpret_cast<float4*>(p) = v; }

__device__ __forceinline__ unsigned short f2bf(float f){
  union { float f; unsigned u; } v; v.f = f;
  unsigned r = v.u + 0x7fffu + ((v.u >> 16) & 1u);   // RNE
  return (unsigned short)(r >> 16);
}
__device__ __forceinline__ float bf2f(unsigned short u){
  union { unsigned u; float f; } v; v.u = ((unsigned)u) << 16;
  return v.f;
}
__device__ __forceinline__ short8v cvt8(float4 a, float4 b){
  short8v r;
  r[0]=(short)f2bf(a.x); r[1]=(short)f2bf(a.y); r[2]=(short)f2bf(a.z); r[3]=(short)f2bf(a.w);
  r[4]=(short)f2bf(b.x); r[5]=(short)f2bf(b.y); r[6]=(short)f2bf(b.z); r[7]=(short)f2bf(b.w);
  return r;
}

__device__ __forceinline__ float wave_sum(float v){
  #pragma unroll
  for (int m = 1; m < 64; m <<= 1) v += __shfl_xor(v, m, 64);
  return v;
}

// async global->LDS (dest = wave-uniform base + lane*size)
typedef __attribute__((address_space(1))) unsigned int gu32;
typedef __attribute__((address_space(3))) unsigned int su32;
__device__ __forceinline__ void gload_lds16(const void* g, void* s){
  __builtin_amdgcn_global_load_lds((const gu32*)g, (su32*)s, 16, 0, 0);
}
__device__ __forceinline__ void gload_lds4(const void* g, void* s){
  __builtin_amdgcn_global_load_lds((const gu32*)g, (su32*)s, 4, 0, 0);
}
__device__ __forceinline__ void barrier_raw(){
  __builtin_amdgcn_sched_barrier(0);
  __builtin_amdgcn_s_barrier();
  __builtin_amdgcn_sched_barrier(0);
}

// ---------------- prep: proto norms + bf16 protos + transposed bf16 weights ----------------
__global__ __launch_bounds__(256) void k_prep(const float* __restrict__ protos,
                                              float* __restrict__ normp2,
                                              unsigned short* __restrict__ pBF,
                                              const float* __restrict__ W_emb,
                                              const float* __restrict__ W1,
                                              const float* __restrict__ W2,
                                              const float* __restrict__ Wmu,
                                              const float* __restrict__ Wvar,
                                              unsigned short* __restrict__ WembT,
                                              unsigned short* __restrict__ W1T,
                                              unsigned short* __restrict__ W2T,
                                              unsigned short* __restrict__ WmuT,
                                              unsigned short* __restrict__ WvarT){
  const int b = blockIdx.x, tid = threadIdx.x;
  if (b < 8){
    const int p = b * 256 + tid;
    const float* row = protos + (size_t)p * CM;
    float s = 0.f;
    #pragma unroll
    for (int k = 0; k < CM; k += 4){
      float4 v = ld4(row + k);
      s += v.x*v.x + v.y*v.y + v.z*v.z + v.w*v.w;
      ushort4 u; u.x = f2bf(v.x); u.y = f2bf(v.y); u.z = f2bf(v.z); u.w = f2bf(v.w);
      *reinterpret_cast<ushort4*>(&pBF[(size_t)p * CM + k]) = u;
    }
    normp2[p] = s;
  } else if (b < 16){
    const int nb = (b - 8) * 8;                  // 8 n-rows of WembT per block
    for (int i = tid; i < 8*512; i += 256){
      const int n = nb + (i >> 9), k = i & 511;
      WembT[n*512 + k] = f2bf(W_emb[k*64 + n]);
    }
  } else if (b == 16){
    for (int i = tid; i < 64*64; i += 256){
      const int n = i >> 6, k = i & 63;
      W1T[n*64 + k] = f2bf(W1[k*64 + n]);
    }
  } else if (b == 17){
    for (int i = tid; i < 128*64; i += 256){
      const int n = i >> 6, k = i & 63;
      W2T[n*64 + k] = f2bf(W2[k*128 + n]);
    }
  } else if (b < 20){
    const int nb = (b - 18) * 64;
    for (int i = tid; i < 64*128; i += 256){
      const int n = nb + (i >> 7), k = i & 127;
      WmuT[n*128 + k] = f2bf(Wmu[k*128 + n]);
    }
  } else {
    const int nb = (b - 20) * 64;
    for (int i = tid; i < 64*128; i += 256){
      const int n = nb + (i >> 7), k = i & 127;
      WvarT[n*128 + k] = f2bf(Wvar[k*128 + n]);
    }
  }
}

// ---------------- mega: MLP + dual GEMM + sample/kld + both proto phases, one kernel ----------------
// FINAL = R10/R13 (empirical optimum of the R7-R14 structure search; 155 us total).
// 512 threads, 8 waves. fwd waves = 4 row-groups x 2 N-halves; mu/sample never leave LDS.
// Proto phases A/B: triple-buffer 16KB chunks, counted vmcnt, 1 raw barrier/chunk.
__global__ __launch_bounds__(512, 4) void mega(const float* __restrict__ x,
    const unsigned short* __restrict__ WembT, const float* __restrict__ b_emb,
    const unsigned short* __restrict__ W1T,   const float* __restrict__ b1,
    const unsigned short* __restrict__ W2T,   const float* __restrict__ b2,
    const unsigned short* __restrict__ WmuT,  const float* __restrict__ bmu,
    const unsigned short* __restrict__ WvarT, const float* __restrict__ bvar,
    const float* __restrict__ epsIn,
    const unsigned short* __restrict__ pBF, const float* __restrict__ normp2,
    const float* __restrict__ protosF,
    float* __restrict__ outA, float* __restrict__ approx_part,
    float* __restrict__ commit_part, float* __restrict__ kld_part)
{
  // 72 KB pool with lifetime overlays:
  //   muS  [0,8192)        alive: dual-epi .. end
  //   approxl (float) [8192,12288)  alive: phase B
  //   Ps 3x8192 @12288     proto buffers; fwd overlays:
  //     Xs  @12288 (Ps0 lo), h1s @16384 (Ps0 hi), h2s @20480 (Ps1 lo),
  //     h3s @24576 (Ps1 hi + Ps2 lo), sS @28672 (Ps2) -- h3s dead before sS write,
  //     sS dead (af_s loaded) before Ps2's first stage (chunk c=1).
  __shared__ __align__(16) unsigned short SH[36864];
  __shared__ float Pn[3][64];
  __shared__ float nm2_s[2][64];
  __shared__ float bw[2][64];
  __shared__ int   iw[2][64];
  __shared__ float sw[2][64];
  __shared__ float srow_s[64];
  __shared__ int   bidx_s[64];
  __shared__ float redbuf[8];

  unsigned short* muS = SH;
  float* approxl      = (float*)(SH + 8192);
  unsigned short* PsU = SH + 12288;
  unsigned short* Xs  = PsU;
  unsigned short* h1s = PsU + 4096;
  unsigned short* h2s = PsU + 8192;
  unsigned short* h3s = PsU + 12288;
  unsigned short* sS  = PsU + 16384;

  const int tid = threadIdx.x;
  const int w = tid >> 6, l = tid & 63;
  const int lr = l >> 4, lc = l & 15;
  const int rowbase = blockIdx.x * 64;

  // ================= fwd portion =================
  const int rq = w & 3, nh = w >> 2;
  const int row = rq*16 + lc;

  // ---- layer 1: h1 = x @ W_emb + b_emb (K=512) ----
  f32x4v acc1[2];
  acc1[0] = (f32x4v){0.f,0.f,0.f,0.f}; acc1[1] = (f32x4v){0.f,0.f,0.f,0.f};
  const int srow = tid >> 3, sq = tid & 7;   // 8 threads/row x 8 floats
  const float* xrow = x + (size_t)(rowbase + srow) * IND + sq*8;
  for (int kc8 = 0; kc8 < 8; kc8++){
    float4 v0 = ld4(xrow + kc8*64);
    float4 v1 = ld4(xrow + kc8*64 + 4);
    __syncthreads();   // previous chunk's Xs reads complete
    *reinterpret_cast<short8v*>(&Xs[(srow*64 + sq*8) ^ ((srow & 7) << 3)]) = cvt8(v0, v1);
    __syncthreads();
    #pragma unroll
    for (int ks = 0; ks < 2; ks++){
      const int ai = (row*64 + ks*32 + lr*8) ^ ((row & 7) << 3);
      short8v af = *reinterpret_cast<const short8v*>(&Xs[ai]);
      #pragma unroll
      for (int nt = 0; nt < 2; nt++){
        const int n = nh*32 + nt*16 + lc;
        short8v bf = *reinterpret_cast<const short8v*>(&WembT[(size_t)n*512 + kc8*64 + ks*32 + lr*8]);
        acc1[nt] = __builtin_amdgcn_mfma_f32_16x16x32_bf16(af, bf, acc1[nt], 0, 0, 0);
      }
    }
  }
  __syncthreads();   // last Xs reads done
  #pragma unroll
  for (int nt = 0; nt < 2; nt++){
    const int col = nh*32 + nt*16 + lc;
    const float bb = b_emb[col];
    #pragma unroll
    for (int r = 0; r < 4; r++){
      const int row2 = rq*16 + lr*4 + r;
      h1s[(row2*64 + col) ^ ((row2 & 7) << 3)] = f2bf(acc1[nt][r] + bb);
    }
  }
  __syncthreads();

  // ---- layer 2: h2 = relu(h1 @ W1 + b1) (K=64) ----
  f32x4v acc2[2];
  acc2[0] = (f32x4v){0.f,0.f,0.f,0.f}; acc2[1] = (f32x4v){0.f,0.f,0.f,0.f};
  #pragma unroll
  for (int ks = 0; ks < 2; ks++){
    const int ai = (row*64 + ks*32 + lr*8) ^ ((row & 7) << 3);
    short8v af = *reinterpret_cast<const short8v*>(&h1s[ai]);
    #pragma unroll
    for (int nt = 0; nt < 2; nt++){
      const int n = nh*32 + nt*16 + lc;
      short8v bf = *reinterpret_cast<const short8v*>(&W1T[(size_t)n*64 + ks*32 + lr*8]);
      acc2[nt] = __builtin_amdgcn_mfma_f32_16x16x32_bf16(af, bf, acc2[nt], 0, 0, 0);
    }
  }
  __syncthreads();
  #pragma unroll
  for (int nt = 0; nt < 2; nt++){
    const int col = nh*32 + nt*16 + lc;
    const float bb = b1[col];
    #pragma unroll
    for (int r = 0; r < 4; r++){
      const int row2 = rq*16 + lr*4 + r;
      h2s[(row2*64 + col) ^ ((row2 & 7) << 3)] = f2bf(fmaxf(acc2[nt][r] + bb, 0.f));
    }
  }
  __syncthreads();

  // ---- layer 3: h3 = relu(h2 @ W2 + b2) (K=64, N=128) ----
  f32x4v acc3[4];
  #pragma unroll
  for (int nt = 0; nt < 4; nt++) acc3[nt] = (f32x4v){0.f,0.f,0.f,0.f};
  #pragma unroll
  for (int ks = 0; ks < 2; ks++){
    const int ai = (row*64 + ks*32 + lr*8) ^ ((row & 7) << 3);
    short8v af = *reinterpret_cast<const short8v*>(&h2s[ai]);
    #pragma unroll
    for (int nt = 0; nt < 4; nt++){
      const int n = nh*64 + nt*16 + lc;
      short8v bf = *reinterpret_cast<const short8v*>(&W2T[(size_t)n*64 + ks*32 + lr*8]);
      acc3[nt] = __builtin_amdgcn_mfma_f32_16x16x32_bf16(af, bf, acc3[nt], 0, 0, 0);
    }
  }
  __syncthreads();
  #pragma unroll
  for (int nt = 0; nt < 4; nt++){
    const int col = nh*64 + nt*16 + lc;
    const float bb = b2[col];
    #pragma unroll
    for (int r = 0; r < 4; r++){
      const int row2 = rq*16 + lr*4 + r;
      h3s[(row2*128 + col) ^ ((row2 & 7) << 3)] = f2bf(fmaxf(acc3[nt][r] + bb, 0.f));
    }
  }
  __syncthreads();

  // ---- dual GEMM: mu / logvar (K=128, N=128) ----
  f32x4v accM[4], accV[4];
  #pragma unroll
  for (int nt = 0; nt < 4; nt++){ accM[nt] = (f32x4v){0.f,0.f,0.f,0.f}; accV[nt] = (f32x4v){0.f,0.f,0.f,0.f}; }
  #pragma unroll
  for (int ks = 0; ks < 4; ks++){
    const int ai = (row*128 + ks*32 + lr*8) ^ ((row & 7) << 3);
    short8v af = *reinterpret_cast<const short8v*>(&h3s[ai]);
    #pragma unroll
    for (int nt = 0; nt < 4; nt++){
      const int n = nh*64 + nt*16 + lc;
      short8v bM = *reinterpret_cast<const short8v*>(&WmuT [(size_t)n*128 + ks*32 + lr*8]);
      short8v bV = *reinterpret_cast<const short8v*>(&WvarT[(size_t)n*128 + ks*32 + lr*8]);
      accM[nt] = __builtin_amdgcn_mfma_f32_16x16x32_bf16(af, bM, accM[nt], 0, 0, 0);
      accV[nt] = __builtin_amdgcn_mfma_f32_16x16x32_bf16(af, bV, accV[nt], 0, 0, 0);
    }
  }
  __syncthreads();   // h3s reads done -> sS overlay (and Ps[0]) now writable

  // stage proto chunk 0 into Ps buf0 early: latency hides under sampling epilogue
  #define STAGE(pc, buf) {                                                        \
    _Pragma("unroll")                                                             \
    for (int j = 0; j < 2; j++){                                                  \
      const int p = w*8 + j*4 + (l >> 4);                                         \
      const int g = l & 15;                                                       \
      gload_lds16(&pBF[(size_t)((pc) + p)*CM + ((g*8) ^ ((p & 7)*8))],            \
                  &PsU[(size_t)(buf)*8192 + (w*8 + j*4)*CM]);                     \
    }                                                                             \
    if (w == 0) gload_lds4(&normp2[(pc) + l], &Pn[buf][0]);                       \
  }
  #define VWAIT_PEND() { if (w == 0) asm volatile("s_waitcnt vmcnt(3)" ::: "memory"); \
                         else        asm volatile("s_waitcnt vmcnt(2)" ::: "memory"); }
  #define VWAIT_ALL()  asm volatile("s_waitcnt vmcnt(0)" ::: "memory")

  STAGE(0, 0);

  // ---- sampling epilogue: mu/sample -> LDS bf16, kld partial, block-local ||mu||^2 ----
  {
    float kl = 0.f;
    float m2[4] = {0.f, 0.f, 0.f, 0.f};
    #pragma unroll
    for (int nt = 0; nt < 4; nt++){
      const int col = nh*64 + nt*16 + lc;
      const float bm = bmu[col], bv = bvar[col];
      #pragma unroll
      for (int r = 0; r < 4; r++){
        const int row2 = rq*16 + lr*4 + r;
        const float mu = accM[nt][r] + bm;
        const float lv = accV[nt][r] + bv;
        const float s2 = __expf(0.5f * lv);
        const float sa = mu + s2 * epsIn[(size_t)(rowbase + row2)*CM + col];
        kl += 1.f + lv - mu*mu - s2*s2;
        m2[r] += mu*mu;
        const int li = (row2*128 + col) ^ ((row2 & 7) << 3);
        muS[li] = f2bf(mu);
        sS [li] = f2bf(sa);
      }
    }
    #pragma unroll
    for (int m = 1; m < 16; m <<= 1){
      #pragma unroll
      for (int r = 0; r < 4; r++) m2[r] += __shfl_xor(m2[r], m, 64);
    }
    if (lc == 0){
      #pragma unroll
      for (int r = 0; r < 4; r++) nm2_s[nh][rq*16 + lr*4 + r] = m2[r];
    }
    const float kw = wave_sum(kl);
    if (l == 0) redbuf[w] = kw;
  }
  __syncthreads();   // muS/sS/nm2_s/redbuf visible
  if (tid == 0) kld_part[blockIdx.x] = redbuf[0]+redbuf[1]+redbuf[2]+redbuf[3]
                                     + redbuf[4]+redbuf[5]+redbuf[6]+redbuf[7];

  // ================= proto portion (R7 v3) =================
  const int rw = w & 1;            // rows half (32 rows)
  const int pw = (w >> 1) & 1;     // protos half of chunk (32)
  const int mat = w >> 2;          // 0: sample/argmin, 1: mu/exp

  const unsigned short* Abase = mat ? muS : sS;
  short8v af[2][4];
  #pragma unroll
  for (int mt = 0; mt < 2; mt++){
    const int ar = rw*32 + mt*16 + lc;
    #pragma unroll
    for (int ks = 0; ks < 4; ks++)
      af[mt][ks] = *reinterpret_cast<const short8v*>(&Abase[(ar*128 + ks*32 + lr*8) ^ ((ar & 7) << 3)]);
  }
  float nmn[8];   // -0.125 * ||mu||^2 per row
  #pragma unroll
  for (int mt = 0; mt < 2; mt++)
    #pragma unroll
    for (int r = 0; r < 4; r++){
      const int rr = rw*32 + mt*16 + lr*4 + r;
      nmn[mt*4+r] = -0.125f * (nm2_s[0][rr] + nm2_s[1][rr]);
    }
  __syncthreads();   // all sS reads done -> approxl overlay writable
  for (int t = tid; t < NP; t += 512) approxl[t] = 0.f;

  float best[8]; int bidx[8]; float sr[8];
  #pragma unroll
  for (int i = 0; i < 8; i++){ best[i] = 3.4e38f; bidx[i] = 0; sr[i] = 0.f; }

  // ---------------- phase A ----------------
  int cur = 0;
  for (int c = 0; c < 32; c++){
    const int nxt = (cur == 2) ? 0 : cur + 1;
    if (c < 31){ STAGE((c+1)*64, nxt); VWAIT_PEND(); }
    else       { VWAIT_ALL(); }
    barrier_raw();
    const float npv0 = Pn[cur][pw*32 + lc];
    const float npv1 = Pn[cur][pw*32 + 16 + lc];
    const unsigned short* pb = &PsU[(size_t)cur*8192];
    f32x4v acc[2][2];
    #pragma unroll
    for (int mt = 0; mt < 2; mt++)
      #pragma unroll
      for (int nt = 0; nt < 2; nt++) acc[mt][nt] = (f32x4v){0.f,0.f,0.f,0.f};
    #pragma unroll
    for (int ks = 0; ks < 4; ks++){
      const int pl0 = pw*32 + lc;
      const int pl1 = pw*32 + 16 + lc;
      short8v pf0 = *reinterpret_cast<const short8v*>(&pb[(pl0*CM + ks*32 + lr*8) ^ ((pl0 & 7) << 3)]);
      short8v pf1 = *reinterpret_cast<const short8v*>(&pb[(pl1*CM + ks*32 + lr*8) ^ ((pl1 & 7) << 3)]);
      #pragma unroll
      for (int mt = 0; mt < 2; mt++){
        acc[mt][0] = __builtin_amdgcn_mfma_f32_16x16x32_bf16(af[mt][ks], pf0, acc[mt][0], 0, 0, 0);
        acc[mt][1] = __builtin_amdgcn_mfma_f32_16x16x32_bf16(af[mt][ks], pf1, acc[mt][1], 0, 0, 0);
      }
    }
    const int pc = c*64;
    if (mat == 0){
      #pragma unroll
      for (int nt = 0; nt < 2; nt++){
        const int pg = pc + pw*32 + nt*16 + lc;
        const float npv = nt ? npv1 : npv0;
        #pragma unroll
        for (int mt = 0; mt < 2; mt++)
          #pragma unroll
          for (int r = 0; r < 4; r++){
            const float sc = fmaf(-2.f, acc[mt][nt][r], npv);
            if (sc < best[mt*4+r]){ best[mt*4+r] = sc; bidx[mt*4+r] = pg; }
          }
      }
    } else {
      #pragma unroll
      for (int nt = 0; nt < 2; nt++){
        const float pvn = -0.125f * (nt ? npv1 : npv0);
        #pragma unroll
        for (int mt = 0; mt < 2; mt++)
          #pragma unroll
          for (int r = 0; r < 4; r++)
            sr[mt*4+r] += __expf(fmaf(0.25f, acc[mt][nt][r], nmn[mt*4+r] + pvn));
      }
    }
    cur = nxt;
  }

  if (mat == 0){
    #pragma unroll
    for (int m = 1; m < 16; m <<= 1){
      #pragma unroll
      for (int i = 0; i < 8; i++){
        const float ob = __shfl_xor(best[i], m, 64);
        const int   oi = __shfl_xor(bidx[i], m, 64);
        if (ob < best[i] || (ob == best[i] && oi < bidx[i])){ best[i] = ob; bidx[i] = oi; }
      }
    }
    if (lc == 0){
      #pragma unroll
      for (int mt = 0; mt < 2; mt++)
        #pragma unroll
        for (int r = 0; r < 4; r++){
          const int rr = rw*32 + mt*16 + lr*4 + r;
          bw[pw][rr] = best[mt*4+r];
          iw[pw][rr] = bidx[mt*4+r];
        }
    }
  } else {
    #pragma unroll
    for (int m = 1; m < 16; m <<= 1){
      #pragma unroll
      for (int i = 0; i < 8; i++) sr[i] += __shfl_xor(sr[i], m, 64);
    }
    if (lc == 0){
      #pragma unroll
      for (int mt = 0; mt < 2; mt++)
        #pragma unroll
        for (int r = 0; r < 4; r++){
          const int rr = rw*32 + mt*16 + lr*4 + r;
          sw[pw][rr] = sr[mt*4+r];
        }
    }
  }
  __syncthreads();
  if (tid < 64){
    float b0 = bw[0][tid]; int i0 = iw[0][tid];
    const float b1 = bw[1][tid]; const int i1 = iw[1][tid];
    if (b1 < b0 || (b1 == b0 && i1 < i0)){ b0 = b1; i0 = i1; }
    bidx_s[tid] = i0;
    srow_s[tid] = sw[0][tid] + sw[1][tid] + (float)NP * EPSV;
  }
  STAGE(0, 0);   // prefetch phase-B chunk 0 (buf0 last read at chunk 30; sync above)
  __syncthreads();

  // out rows = protos[idx] (fp32) + commitment partial (mu from LDS)
  {
    const int orow = tid >> 3, cp = tid & 7;
    const int rowg = rowbase + orow;
    const int idx = bidx_s[orow];
    float cl = 0.f;
    #pragma unroll
    for (int c4 = 0; c4 < 4; c4++){
      const int cc = c4*32 + cp*4;
      float4 q = ld4(protosF + (size_t)idx * CM + cc);
      const int li = (orow*128 + cc) ^ ((orow & 7) << 3);
      ushort4 mb = *reinterpret_cast<const ushort4*>(&muS[li]);
      st4(outA + (size_t)rowg * CM + cc, q);
      const float dx=q.x-bf2f(mb.x), dy=q.y-bf2f(mb.y), dz=q.z-bf2f(mb.z), dw=q.w-bf2f(mb.w);
      cl += dx*dx + dy*dy + dz*dz + dw*dw;
    }
    const float cw = wave_sum(cl);
    if (l == 0) redbuf[w] = cw;
  }
  float rs[8]; float epsc = 0.f;
  #pragma unroll
  for (int mt = 0; mt < 2; mt++)
    #pragma unroll
    for (int r = 0; r < 4; r++){
      rs[mt*4+r] = 1.0f / srow_s[rw*32 + mt*16 + lr*4 + r];
      epsc += rs[mt*4+r];
    }
  epsc *= EPSV;
  if (mat == 0){
    #pragma unroll
    for (int mt = 0; mt < 2; mt++){
      const int ar = rw*32 + mt*16 + lc;
      #pragma unroll
      for (int ks = 0; ks < 4; ks++)
        af[mt][ks] = *reinterpret_cast<const short8v*>(&muS[(ar*128 + ks*32 + lr*8) ^ ((ar & 7) << 3)]);
    }
  }
  __syncthreads();
  if (tid == 0) commit_part[blockIdx.x] = redbuf[0]+redbuf[1]+redbuf[2]+redbuf[3]
                                        + redbuf[4]+redbuf[5]+redbuf[6]+redbuf[7];

  // ---------------- phase B ----------------
  const int pq = w >> 1;   // 16-proto quarter
  cur = 0;
  for (int c = 0; c < 32; c++){
    const int nxt = (cur == 2) ? 0 : cur + 1;
    if (c < 31){ STAGE((c+1)*64, nxt); VWAIT_PEND(); }
    else       { VWAIT_ALL(); }
    barrier_raw();
    const int pl = pq*16 + lc;
    const float npv = Pn[cur][pl];
    const unsigned short* pb = &PsU[(size_t)cur*8192];
    f32x4v accB[2];
    accB[0] = (f32x4v){0.f,0.f,0.f,0.f};
    accB[1] = (f32x4v){0.f,0.f,0.f,0.f};
    #pragma unroll
    for (int ks = 0; ks < 4; ks++){
      short8v pf = *reinterpret_cast<const short8v*>(&pb[(pl*CM + ks*32 + lr*8) ^ ((pl & 7) << 3)]);
      accB[0] = __builtin_amdgcn_mfma_f32_16x16x32_bf16(af[0][ks], pf, accB[0], 0, 0, 0);
      accB[1] = __builtin_amdgcn_mfma_f32_16x16x32_bf16(af[1][ks], pf, accB[1], 0, 0, 0);
    }
    const float pvn = -0.125f * npv;
    float cs = epsc;
    #pragma unroll
    for (int mt = 0; mt < 2; mt++)
      #pragma unroll
      for (int r = 0; r < 4; r++){
        const float e = __expf(fmaf(0.25f, accB[mt][r], nmn[mt*4+r] + pvn));
        cs = fmaf(e, rs[mt*4+r], cs);
      }
    cs += __shfl_xor(cs, 16, 64);
    cs += __shfl_xor(cs, 32, 64);
    if (l < 16) atomicAdd(&approxl[c*64 + pq*16 + lc], cs);
    cur = nxt;
  }
  __syncthreads();
  for (int t = tid; t < NP; t += 512)
    approx_part[(size_t)blockIdx.x * NP + t] = approxl[t];
  #undef STAGE
  #undef VWAIT_PEND
  #undef VWAIT_ALL
}

// ---------------- final reductions ----------------
__global__ __launch_bounds__(256) void k4a(const float* __restrict__ approx_part,
                                           float* __restrict__ ent_part){
  __shared__ float red[128];
  const int tid = threadIdx.x;
  const int p = blockIdx.x * 32 + (tid & 31);
  const int slice = tid >> 5;            // 0..7
  float s = 0.f;
  for (int b = slice; b < 512; b += 8) s += approx_part[(size_t)b * NP + p];
  s += __shfl_xor(s, 32, 64);
  if ((tid & 63) < 32) red[(tid >> 6)*32 + (tid & 31)] = s;
  __syncthreads();
  if (tid < 32){
    const float a = (red[tid] + red[32+tid] + red[64+tid] + red[96+tid]) * (1.0f / 32768.0f);
    float t = -a * logf(a);
    #pragma unroll
    for (int m = 1; m < 32; m <<= 1) t += __shfl_xor(t, m, 32);
    if (tid == 0) ent_part[blockIdx.x] = t;
  }
}

__global__ __launch_bounds__(256) void k4b(const float* __restrict__ kld_part,
                                           const float* __restrict__ commit_part,
                                           const float* __restrict__ ent_part,
                                           float* __restrict__ outs){
  __shared__ float redbuf[8];
  const int tid = threadIdx.x;
  float k = 0.f, c = 0.f;
  for (int i = tid; i < 512; i += 256){ k += kld_part[i]; c += commit_part[i]; }
  float kw = wave_sum(k), cw = wave_sum(c);
  if ((tid & 63) == 0){ redbuf[tid >> 6] = kw; redbuf[4 + (tid >> 6)] = cw; }
  __syncthreads();
  if (tid == 0){
    float ks = redbuf[0] + redbuf[1] + redbuf[2] + redbuf[3];
    float cs = redbuf[4] + redbuf[5] + redbuf[6] + redbuf[7];
    float es = 0.f;
    for (int i = 0; i < 64; i++) es += ent_part[i];
    float kld = -0.5f * ks / 32768.0f;
    float m = cs / (32768.0f * 128.0f);
    float vq = BETA * m + m + ENT_W * es;
    outs[0] = kld + vq;   // KL_W = 1
    outs[1] = kld;
  }
}

extern "C" void kernel_launch(void* const* d_in, const int* in_sizes, int n_in,
                              void* d_out, int out_size, void* d_ws, size_t ws_size,
                              hipStream_t stream){
  const float* x      = (const float*)d_in[0];
  const float* epsIn  = (const float*)d_in[1];
  const float* W_emb  = (const float*)d_in[2];
  const float* b_emb  = (const float*)d_in[3];
  const float* W1     = (const float*)d_in[4];
  const float* b1     = (const float*)d_in[5];
  const float* W2     = (const float*)d_in[6];
  const float* b2     = (const float*)d_in[7];
  const float* W_mu   = (const float*)d_in[8];
  const float* b_mu   = (const float*)d_in[9];
  const float* W_var  = (const float*)d_in[10];
  const float* b_var  = (const float*)d_in[11];
  const float* protos = (const float*)d_in[12];
  float* out = (float*)d_out;
  float* ws = (float*)d_ws;

  const size_t M1 = 1024u * 1024u;
  float* approx_part = ws;                    // [0,1M) floats (512*2048)
  float* tail = ws + M1;
  float* normp2      = tail;                  // 2048
  float* kld_part    = normp2 + 2048;         // 512
  float* commit_part = kld_part + 512;        // 512
  float* ent_part    = commit_part + 512;     // 64
  unsigned short* pBF   = (unsigned short*)(ent_part + 64);  // 2048*128
  unsigned short* WembT = pBF + (size_t)NP*CM;               // 64*512
  unsigned short* W1T   = WembT + 64*512;                    // 64*64
  unsigned short* W2T   = W1T + 64*64;                       // 128*64
  unsigned short* WmuT  = W2T + 128*64;                      // 128*128
  unsigned short* WvarT = WmuT + 128*128;                    // 128*128

  k_prep<<<22, 256, 0, stream>>>(protos, normp2, pBF, W_emb, W1, W2, W_mu, W_var,
                                 WembT, W1T, W2T, WmuT, WvarT);
  mega<<<NB/64, 512, 0, stream>>>(x, WembT, b_emb, W1T, b1, W2T, b2,
                                  WmuT, b_mu, WvarT, b_var, epsIn,
                                  pBF, normp2, protos,
                                  out, approx_part, commit_part, kld_part);
  k4a<<<64, 256, 0, stream>>>(approx_part, ent_part);
  k4b<<<1, 256, 0, stream>>>(kld_part, commit_part, ent_part, out + (size_t)NB * CM);
}